// Round 12
// baseline (45.539 us; speedup 1.0000x reference)
//
#include <hip/hip_runtime.h>

#define WI 4096
#define HI 4096
#define WO 4090
#define HO 4090
#define TH 6             // output rows per block (< 7 -> no accumulator ring)
#define IH 12            // staged input rows
#define IWP 1032         // floats per LDS row (1030 needed, 16B multiple)
#define CPR 258          // 16-byte chunks per LDS row
#define ACH (8*CPR)      // phase-A chunks (input rows 0..7)  = 2064
#define NCH (IH*CPR)     // total chunks                      = 3096

__device__ __forceinline__ void gl_lds16(const float* g, float* l) {
    __builtin_amdgcn_global_load_lds(
        (const __attribute__((address_space(1))) void*)g,
        (__attribute__((address_space(3))) void*)l, 16, 0, 0);
}

__global__ __launch_bounds__(256, 3) void conv7x7(
    const float* __restrict__ x, const float* __restrict__ wgt,
    const float* __restrict__ bias, float* __restrict__ out)
{
    __shared__ float lds[IH * IWP];   // 49,536 B -> 3 blocks/CU (12 waves)

    const int tid = threadIdx.x;
    const int x0  = blockIdx.x * 1024;
    const int y0  = blockIdx.y * TH;

    // weights + bias: uniform addresses -> SGPR-resident scalar loads
    float Wt[49];
    #pragma unroll
    for (int i = 0; i < 49; ++i) Wt[i] = wgt[i];
    const float bb = bias[0];

    const int cx  = 4 * tid;            // local first output col (16B aligned)
    const int gx  = x0 + cx;            // global first output col
    const bool st0 = (gx + 1 < WO);     // mask for cols 0,1
    const bool st1 = (gx + 3 < WO);     // mask for cols 2,3

    // stage chunks [c0,c0+n): chunk c -> LDS floats [4c,4c+4), src row c/258,
    // col 4*(c%258). LDS dest per wave-instr = uniform base + lane*16 (linear
    // as required); per-lane global src, clamped (clamped data only ever
    // feeds masked-off outputs).
    auto stage = [&](int c0, int n) {
        for (int c = c0 + tid; c < c0 + n; c += 256) {
            const int rr = c / CPR;            // magic-mul div
            const int c4 = c - rr * CPR;
            int gy = y0 + rr;       gy  = gy  < HI ? gy : HI - 1;
            int gxs = x0 + c4 * 4;  gxs = gxs <= WI - 4 ? gxs : WI - 4;
            gl_lds16(x + (size_t)gy * WI + gxs, lds + c * 4);
        }
    };

    float acc[TH][4];
    #pragma unroll
    for (int o = 0; o < TH; ++o)
        #pragma unroll
        for (int c = 0; c < 4; ++c) acc[o][c] = 0.f;

    // one fully-static row step: 2x ds_read_b128 + 1x ds_read_b64 + FMA
    #define DOROW(r)                                                        \
    {                                                                       \
        const float* lrow_ = lds + (r) * IWP + cx;                          \
        const float4 q0 = *(const float4*)(lrow_ + 0);                      \
        const float4 q1 = *(const float4*)(lrow_ + 4);                      \
        const float2 q2 = *(const float2*)(lrow_ + 8);                      \
        const float f_[10] = {q0.x,q0.y,q0.z,q0.w,                          \
                              q1.x,q1.y,q1.z,q1.w,q2.x,q2.y};               \
        _Pragma("unroll")                                                   \
        for (int ky = 0; ky < 7; ++ky) {                                    \
            const int oy = (r) - ky;               /* static */             \
            if (oy >= 0 && oy < TH) {                                       \
                _Pragma("unroll")                                           \
                for (int kx = 0; kx < 7; ++kx) {                            \
                    const float w_ = Wt[ky * 7 + kx];                       \
                    acc[oy][0] += w_ * f_[kx + 0];                          \
                    acc[oy][1] += w_ * f_[kx + 1];                          \
                    acc[oy][2] += w_ * f_[kx + 2];                          \
                    acc[oy][3] += w_ * f_[kx + 3];                          \
                }                                                           \
            }                                                               \
        }                                                                   \
        if ((r) >= 6) {                            /* static */             \
            const int oy = (r) - 6;                /* completes exactly once */\
            const int gy = y0 + oy;                                         \
            if (gy < HO) {                                                  \
                float* po_ = out + (size_t)gy * WO + gx;                    \
                if (st0) *(float2*)(po_ + 0) =                              \
                    make_float2(acc[oy][0] + bb, acc[oy][1] + bb);          \
                if (st1) *(float2*)(po_ + 2) =                              \
                    make_float2(acc[oy][2] + bb, acc[oy][3] + bb);          \
            }                                                               \
        }                                                                   \
    }

    // ---- phase A: stage input rows 0..7; exposed drain once per block ----
    stage(0, ACH);
    __syncthreads();

    // ---- issue phase-B stage (rows 8..11), fire-and-forget ----
    stage(ACH, NCH - ACH);

    // ---- compute A: rows 0..7 (~3100 cyc, covers stage-B HBM latency) ----
    #pragma unroll
    for (int r = 0; r < 8; ++r) DOROW(r)

    __syncthreads();   // vmcnt(0) drain of stage-B: aged a full phase -> ~free

    // ---- compute B: rows 8..11 ----
    #pragma unroll
    for (int r = 8; r < 12; ++r) DOROW(r)

    #undef DOROW
}

extern "C" void kernel_launch(void* const* d_in, const int* in_sizes, int n_in,
                              void* d_out, int out_size, void* d_ws, size_t ws_size,
                              hipStream_t stream) {
    const float* x = (const float*)d_in[0];
    const float* w = (const float*)d_in[1];
    const float* b = (const float*)d_in[2];
    float* out = (float*)d_out;
    // x: 4 stripes x 1024 cols (last stripe masks cols >= 4090)
    // y: ceil(4090/6) = 682 segments
    dim3 grid(4, 682);
    conv7x7<<<grid, 256, 0, stream>>>(x, w, b, out);
}